// Round 1
// baseline (171.913 us; speedup 1.0000x reference)
//
#include <hip/hip_runtime.h>
#include <stdint.h>

#define NTH   1024
#define NPOS  33600
#define KTOP  1000
#define NBIN  2048
#define CAP   4096

// sizes per level
#define HW0 25600  // 160x160, stride 8
#define HW1 6400   // 80x80,  stride 16
#define HW2 1600   // 40x40,  stride 32

__device__ __forceinline__ uint32_t mono_key(float x) {
    uint32_t u = __float_as_uint(x);
    // monotone map: negative floats -> ~u (descending bits become ascending),
    // positive -> set sign bit. Result: unsigned compare == float compare.
    return (u & 0x80000000u) ? ~u : (u | 0x80000000u);
}

__global__ __launch_bounds__(NTH) void topk_decode_kernel(
    const float* __restrict__ cls0, const float* __restrict__ bb0,
    const float* __restrict__ cls1, const float* __restrict__ bb1,
    const float* __restrict__ cls2, const float* __restrict__ bb2,
    float* __restrict__ out, int B)
{
    const int b   = blockIdx.x;
    const int tid = threadIdx.x;

    __shared__ uint32_t histA[NBIN];
    __shared__ uint32_t histB[NBIN];
    __shared__ unsigned long long buf[CAP];
    __shared__ int s_boundary;
    __shared__ int s_cnt;

    for (int i = tid; i < NBIN; i += NTH) histA[i] = 0u;
    if (tid == 0) s_cnt = 0;
    __syncthreads();

    const float* cb0 = cls0 + (size_t)b * HW0;
    const float* cb1 = cls1 + (size_t)b * HW1;
    const float* cb2 = cls2 + (size_t)b * HW2;

    // ---- phase 1: histogram of top-11 bits of monotone logit key ----
    for (int i = tid; i < NPOS; i += NTH) {
        float v;
        if (i < HW0)            v = cb0[i];
        else if (i < HW0 + HW1) v = cb1[i - HW0];
        else                    v = cb2[i - HW0 - HW1];
        uint32_t k = mono_key(v);
        atomicAdd(&histA[k >> 21], 1u);
    }
    __syncthreads();

    // ---- suffix scan (Hillis-Steele, double buffer) ----
    uint32_t* A = histA; uint32_t* Bp = histB;
    for (int off = 1; off < NBIN; off <<= 1) {
        for (int i = tid; i < NBIN; i += NTH)
            Bp[i] = A[i] + ((i + off < NBIN) ? A[i + off] : 0u);
        __syncthreads();
        uint32_t* t = A; A = Bp; Bp = t;
    }
    // A[bin] = count of elements with bin' >= bin (non-increasing in bin)
    for (int bin = tid; bin < NBIN; bin += NTH) {
        uint32_t c     = A[bin];
        uint32_t cnext = (bin + 1 < NBIN) ? A[bin + 1] : 0u;
        if (c >= (uint32_t)KTOP && cnext < (uint32_t)KTOP) s_boundary = bin;
    }
    __syncthreads();
    const uint32_t boundary = (uint32_t)s_boundary;

    // ---- phase 2: compact candidates (bin >= boundary) ----
    for (int i = tid; i < NPOS; i += NTH) {
        float v;
        if (i < HW0)            v = cb0[i];
        else if (i < HW0 + HW1) v = cb1[i - HW0];
        else                    v = cb2[i - HW0 - HW1];
        uint32_t k = mono_key(v);
        if ((k >> 21) >= boundary) {
            int pos = atomicAdd(&s_cnt, 1);
            if (pos < CAP)
                buf[pos] = ((unsigned long long)k << 16)
                         | (unsigned long long)(65535 - i); // idx asc on key tie
        }
    }
    __syncthreads();
    int cnt = s_cnt; if (cnt > CAP) cnt = CAP;
    int M = 1024; while (M < cnt) M <<= 1;        // pow2, <= CAP
    for (int i = cnt + tid; i < M; i += NTH) buf[i] = 0ull;
    __syncthreads();

    // ---- bitonic sort descending over M elements ----
    for (int k = 2; k <= M; k <<= 1) {
        for (int j = k >> 1; j > 0; j >>= 1) {
            for (int i = tid; i < M; i += NTH) {
                int l = i ^ j;
                if (l > i) {
                    unsigned long long a = buf[i], c = buf[l];
                    bool sw = ((i & k) == 0) ? (a < c) : (a > c);
                    if (sw) { buf[i] = c; buf[l] = a; }
                }
            }
            __syncthreads();
        }
    }

    // ---- epilogue: decode top-1000, gather boxes, write ----
    const size_t score_base = (size_t)B * KTOP * 4;
    for (int r = tid; r < KTOP; r += NTH) {
        unsigned long long ck = buf[r];
        uint32_t k = (uint32_t)(ck >> 16);
        int idx    = 65535 - (int)(ck & 0xFFFFull);

        // invert monotone map
        uint32_t u = (k & 0x80000000u) ? (k ^ 0x80000000u) : ~k;
        float logit = __uint_as_float(u);
        float score = 1.0f / (1.0f + expf(-logit));

        int j, w, stride, hw;
        const float* bb;
        if (idx < HW0)            { j = idx;             w = 160; stride = 8;  hw = HW0; bb = bb0 + (size_t)b * 4 * HW0; }
        else if (idx < HW0 + HW1) { j = idx - HW0;       w = 80;  stride = 16; hw = HW1; bb = bb1 + (size_t)b * 4 * HW1; }
        else                      { j = idx - HW0 - HW1; w = 40;  stride = 32; hw = HW2; bb = bb2 + (size_t)b * 4 * HW2; }

        float px = (float)((j % w) * stride);
        float py = (float)((j / w) * stride);
        float l0 = bb[j];
        float t0 = bb[hw + j];
        float r0 = bb[2 * hw + j];
        float d0 = bb[3 * hw + j];

        float* ob = out + ((size_t)b * KTOP + r) * 4;
        ob[0] = px - l0;
        ob[1] = py - t0;
        ob[2] = px + r0;
        ob[3] = py + d0;
        out[score_base + (size_t)b * KTOP + r] = score;
    }
}

extern "C" void kernel_launch(void* const* d_in, const int* in_sizes, int n_in,
                              void* d_out, int out_size, void* d_ws, size_t ws_size,
                              hipStream_t stream) {
    // setup_inputs dict order: cls0, bbox0, cls1, bbox1, cls2, bbox2
    const float* cls0 = (const float*)d_in[0];
    const float* bb0  = (const float*)d_in[1];
    const float* cls1 = (const float*)d_in[2];
    const float* bb1  = (const float*)d_in[3];
    const float* cls2 = (const float*)d_in[4];
    const float* bb2  = (const float*)d_in[5];
    float* out = (float*)d_out;

    int B = in_sizes[0] / HW0;  // 128
    topk_decode_kernel<<<B, NTH, 0, stream>>>(cls0, bb0, cls1, bb1, cls2, bb2, out, B);
}